// Round 5
// baseline (511.193 us; speedup 1.0000x reference)
//
#include <hip/hip_runtime.h>
#include <hip/hip_bf16.h>

#define N 8192
#define IND 128
#define OUTD 128
#define JC 8
#define JLEN 1024   /* N/JC */
#define OSTEPS 8    /* JLEN/128, outer step = 128 j (512B/row DRAM burst) */

typedef float f32x4 __attribute__((ext_vector_type(4)));
typedef short s16x8 __attribute__((ext_vector_type(8)));
typedef _Float16 f16;
typedef _Float16 f16x4 __attribute__((ext_vector_type(4)));

static __device__ inline unsigned short f2bf(float f) {
    union { float f; unsigned u; } v; v.f = f;
    unsigned u = v.u + 0x7fffu + ((v.u >> 16) & 1u);
    return (unsigned short)(u >> 16);
}
static __device__ inline float bf2f(unsigned short b) {
    union { unsigned u; float f; } v; v.u = ((unsigned)b) << 16;
    return v.f;
}

// ---------------------------------------------------------------------------
// Kernel 1: h = x @ W  (bf16 MFMA), store transposed bf16 hT[c][i] (128 x N).
// ---------------------------------------------------------------------------
__global__ __launch_bounds__(256) void k1_xw(const float* __restrict__ x,
                                             const float* __restrict__ W,
                                             unsigned short* __restrict__ hT) {
    __shared__ unsigned short Wl[128 * 130];
    const int tid = threadIdx.x;
    {
        int k = tid >> 1, n0 = (tid & 1) * 64;
        const float4* src = (const float4*)(W + k * 128 + n0);
#pragma unroll
        for (int v = 0; v < 16; ++v) {
            float4 f = src[v];
            int base = k * 130 + n0 + v * 4;
            Wl[base + 0] = f2bf(f.x);
            Wl[base + 1] = f2bf(f.y);
            Wl[base + 2] = f2bf(f.z);
            Wl[base + 3] = f2bf(f.w);
        }
    }
    __syncthreads();
    const int wave = tid >> 6, lane = tid & 63;
    const int m = lane & 15, quad = lane >> 4;
    const int ibase = blockIdx.x * 64 + wave * 16;
    const int irow = ibase + m;

    f32x4 acc[8];
#pragma unroll
    for (int t = 0; t < 8; ++t) acc[t] = (f32x4){0.f, 0.f, 0.f, 0.f};

#pragma unroll
    for (int ks = 0; ks < 4; ++ks) {
        const int k0 = ks * 32 + quad * 8;
        const float4* xp = (const float4*)(x + (size_t)irow * 128 + k0);
        float4 xa = xp[0], xb = xp[1];
        s16x8 afrag;
        afrag[0] = (short)f2bf(xa.x); afrag[1] = (short)f2bf(xa.y);
        afrag[2] = (short)f2bf(xa.z); afrag[3] = (short)f2bf(xa.w);
        afrag[4] = (short)f2bf(xb.x); afrag[5] = (short)f2bf(xb.y);
        afrag[6] = (short)f2bf(xb.z); afrag[7] = (short)f2bf(xb.w);
#pragma unroll
        for (int nt = 0; nt < 8; ++nt) {
            const int n = nt * 16 + m;
            s16x8 bfrag;
#pragma unroll
            for (int j = 0; j < 8; ++j)
                bfrag[j] = (short)Wl[(k0 + j) * 130 + n];
            acc[nt] = __builtin_amdgcn_mfma_f32_16x16x32_bf16(afrag, bfrag, acc[nt], 0, 0, 0);
        }
    }
#pragma unroll
    for (int nt = 0; nt < 8; ++nt) {
        const int c = nt * 16 + m;
        const int i0 = ibase + quad * 4;
        ushort4 pk;
        pk.x = f2bf(acc[nt][0]); pk.y = f2bf(acc[nt][1]);
        pk.z = f2bf(acc[nt][2]); pk.w = f2bf(acc[nt][3]);
        *(ushort4*)(hT + (size_t)c * N + i0) = pk;
    }
}

// ---------------------------------------------------------------------------
// Kernel 2: per-node separable arrays.
// w_ij = exp(leaky(es_i + ed_j)) = max(A_i*B_j, C_i*D_j);  BD[j]={B0,D0,B1,D1}
// ---------------------------------------------------------------------------
__global__ __launch_bounds__(256) void k2_e(const unsigned short* __restrict__ hT,
                                            const float* __restrict__ a_src,
                                            const float* __restrict__ a_dst,
                                            float* __restrict__ As, float* __restrict__ Cs,
                                            float4* __restrict__ BD) {
    const int i = blockIdx.x * 256 + threadIdx.x;
    float es0 = 0.f, ed0 = 0.f, es1 = 0.f, ed1 = 0.f;
#pragma unroll 8
    for (int c = 0; c < 128; ++c) {
        float v = bf2f(hT[(size_t)c * N + i]);
        float as = a_src[c], ad = a_dst[c];
        if (c < 64) { es0 += v * as; ed0 += v * ad; }
        else        { es1 += v * as; ed1 += v * ad; }
    }
    As[i]     = __expf(es0);
    As[N + i] = __expf(es1);
    Cs[i]     = __expf(0.2f * es0);
    Cs[N + i] = __expf(0.2f * es1);
    float4 bd;
    bd.x = __expf(ed0); bd.y = __expf(0.2f * ed0);
    bd.z = __expf(ed1); bd.w = __expf(0.2f * ed1);
    BD[i] = bd;
}

// ---------------------------------------------------------------------------
// Kernel 3 (main): barrier-free K-loop, adj+hT direct-to-VGPR.
//  - outer step = 128 j -> each adj row fetched in 512B bursts (DRAM-page
//    friendly; the 128B/row/step pattern of R1-R4 collapsed HBM to 0.9 TB/s)
//  - adj for os+1 prefetched into regs while os computes (no barriers to
//    drain it; per-wave vmcnt only)
//  - hT fragment loads issued before the P-compute that hides their latency
//  - BD broadcast from LDS, staged once (padded: quad addrs on distinct banks)
// grid = (8 j-chunks, 128 i-tiles); block = 256 thr = 4 waves, 16 rows/wave.
// ---------------------------------------------------------------------------
__global__ __launch_bounds__(256, 2) void k3_main(const float* __restrict__ adj,
                                                  const unsigned short* __restrict__ hT,
                                                  const float* __restrict__ As,
                                                  const float* __restrict__ Cs,
                                                  const float4* __restrict__ BD,
                                                  f16* __restrict__ Up,
                                                  float* __restrict__ Lp) {
    __shared__ float4 BDl[JLEN + JLEN / 8];   // 18 KB, padded t+(t>>3)
    const int tid = threadIdx.x;
    const int wave = tid >> 6, lane = tid & 63;
    const int m = lane & 15, quad = lane >> 4;
    const int ibase = blockIdx.y * 64 + wave * 16;
    const int irow = ibase + m;
    const int jc = blockIdx.x;
    const int j0 = jc * JLEN;

    // stage BD once (padded scatter -> plain ds_write)
    for (int t = tid; t < JLEN; t += 256) BDl[t + (t >> 3)] = BD[j0 + t];

    const float A0 = As[irow], C0 = Cs[irow];
    const float A1 = As[N + irow], C1 = Cs[N + irow];

    f32x4 acc[2][4];
#pragma unroll
    for (int h = 0; h < 2; ++h)
#pragma unroll
        for (int nt = 0; nt < 4; ++nt) acc[h][nt] = (f32x4){0.f, 0.f, 0.f, 0.f};
    float ls0 = 0.f, ls1 = 0.f;

    const float* adjrow = adj + (size_t)irow * N + j0;
    __syncthreads();

    // adj regs: [buf][kc*2+half], 8 float4 per outer step (32 j for this lane)
    float4 aj[2][8];
#pragma unroll
    for (int kc = 0; kc < 4; ++kc) {
        aj[0][kc * 2]     = *(const float4*)(adjrow + kc * 32 + quad * 8);
        aj[0][kc * 2 + 1] = *(const float4*)(adjrow + kc * 32 + quad * 8 + 4);
    }

#pragma unroll
    for (int os = 0; os < OSTEPS; ++os) {
        const int cur = os & 1, nxt = cur ^ 1;
        const int osn = (os < OSTEPS - 1) ? os + 1 : os;  // last: benign reload
        // prefetch next outer step's adj (512B/row burst, covered by 4 kc's compute)
#pragma unroll
        for (int kc = 0; kc < 4; ++kc) {
            aj[nxt][kc * 2]     = *(const float4*)(adjrow + osn * 128 + kc * 32 + quad * 8);
            aj[nxt][kc * 2 + 1] = *(const float4*)(adjrow + osn * 128 + kc * 32 + quad * 8 + 4);
        }
#pragma unroll
        for (int kc = 0; kc < 4; ++kc) {
            const int jq = j0 + os * 128 + kc * 32 + quad * 8;
            // hT fragments for this kc — issued before P-compute hides L2 latency
            s16x8 h0[4], h1[4];
#pragma unroll
            for (int nt = 0; nt < 4; ++nt) {
                h0[nt] = *(const s16x8*)(hT + (size_t)(nt * 16 + m) * N + jq);
                h1[nt] = *(const s16x8*)(hT + (size_t)(nt * 16 + m + 64) * N + jq);
            }
            float ajv[8];
            *(float4*)(ajv)     = aj[cur][kc * 2];
            *(float4*)(ajv + 4) = aj[cur][kc * 2 + 1];
            const int bb = os * 128 + kc * 32 + quad * 8;
            const int bidx = bb + (bb >> 3);
            s16x8 p0, p1;
#pragma unroll
            for (int jj = 0; jj < 8; ++jj) {
                float4 bd = BDl[bidx + jj];
                float w0 = fmaxf(A0 * bd.x, C0 * bd.y);
                float pv0 = ajv[jj] * w0;
                ls0 += pv0;
                p0[jj] = (short)f2bf(pv0);
                float w1 = fmaxf(A1 * bd.z, C1 * bd.w);
                float pv1 = ajv[jj] * w1;
                ls1 += pv1;
                p1[jj] = (short)f2bf(pv1);
            }
#pragma unroll
            for (int nt = 0; nt < 4; ++nt) {
                acc[0][nt] = __builtin_amdgcn_mfma_f32_16x16x32_bf16(p0, h0[nt], acc[0][nt], 0, 0, 0);
                acc[1][nt] = __builtin_amdgcn_mfma_f32_16x16x32_bf16(p1, h1[nt], acc[1][nt], 0, 0, 0);
            }
        }
    }

    ls0 += __shfl_xor(ls0, 16, 64);
    ls0 += __shfl_xor(ls0, 32, 64);
    ls1 += __shfl_xor(ls1, 16, 64);
    ls1 += __shfl_xor(ls1, 32, 64);

    f16* Ub = Up + (size_t)jc * N * 128;
#pragma unroll
    for (int h = 0; h < 2; ++h)
#pragma unroll
        for (int nt = 0; nt < 4; ++nt) {
            const int c = h * 64 + nt * 16 + m;
            const int ib = ibase + quad * 4;
#pragma unroll
            for (int r = 0; r < 4; ++r)
                Ub[(size_t)(ib + r) * 128 + c] = (f16)acc[h][nt][r];
        }
    if (quad == 0) {
        Lp[((size_t)jc * 2 + 0) * N + irow] = ls0;
        Lp[((size_t)jc * 2 + 1) * N + irow] = ls1;
    }
}

// ---------------------------------------------------------------------------
// Kernel 4: sum fp16 partials over j-chunks, divide by row-sum.
// ---------------------------------------------------------------------------
__global__ __launch_bounds__(256) void k4_reduce(const f16* __restrict__ Up,
                                                 const float* __restrict__ Lp,
                                                 float* __restrict__ out) {
    const int base = (blockIdx.x * 256 + threadIdx.x) * 4;
    const int i = base >> 7, c = base & 127, h = c >> 6;
    float su0 = 0.f, su1 = 0.f, su2 = 0.f, su3 = 0.f, sl = 0.f;
#pragma unroll
    for (int jcc = 0; jcc < JC; ++jcc) {
        f16x4 u = *(const f16x4*)(Up + (size_t)jcc * N * 128 + base);
        su0 += (float)u[0]; su1 += (float)u[1];
        su2 += (float)u[2]; su3 += (float)u[3];
        sl += Lp[((size_t)jcc * 2 + h) * N + i];
    }
    float inv = 1.0f / sl;
    float4 o; o.x = su0 * inv; o.y = su1 * inv; o.z = su2 * inv; o.w = su3 * inv;
    *(float4*)(out + base) = o;
}

extern "C" void kernel_launch(void* const* d_in, const int* in_sizes, int n_in,
                              void* d_out, int out_size, void* d_ws, size_t ws_size,
                              hipStream_t stream) {
    const float* x     = (const float*)d_in[0];
    const float* adj   = (const float*)d_in[1];
    const float* W     = (const float*)d_in[2];
    const float* a_src = (const float*)d_in[3];
    const float* a_dst = (const float*)d_in[4];
    float* out = (float*)d_out;
    char* ws = (char*)d_ws;

    size_t off = 0;
    unsigned short* hT = (unsigned short*)(ws + off); off += (size_t)128 * N * 2;
    float* As = (float*)(ws + off); off += (size_t)2 * N * 4;
    float* Cs = (float*)(ws + off); off += (size_t)2 * N * 4;
    float4* BD = (float4*)(ws + off); off += (size_t)N * 16;

    f16* Up = (f16*)(ws + off);
    float* Lp = (float*)(ws + off + (size_t)JC * N * 128 * 2);

    k1_xw<<<N / 64, 256, 0, stream>>>(x, W, hT);
    k2_e<<<N / 256, 256, 0, stream>>>(hT, a_src, a_dst, As, Cs, BD);
    dim3 g3(JC, N / 64);
    k3_main<<<g3, 256, 0, stream>>>(adj, hT, As, Cs, BD, Up, Lp);
    k4_reduce<<<(N * 128) / (256 * 4), 256, 0, stream>>>(Up, Lp, out);
}